// Round 8
// baseline (255.740 us; speedup 1.0000x reference)
//
#include <hip/hip_runtime.h>

#define D_IN 128
#define D_HID 256
#define CH 1024
#define MPAD 50048   // 782 * 64

typedef short bf16x8 __attribute__((ext_vector_type(8)));
typedef float f32x4 __attribute__((ext_vector_type(4)));
typedef float f32x16 __attribute__((ext_vector_type(16)));
typedef unsigned short ushort8 __attribute__((ext_vector_type(8)));

#define AS1 __attribute__((address_space(1)))
#define AS3 __attribute__((address_space(3)))

__device__ __forceinline__ unsigned short f2bf_rne(float x) {
  unsigned int u = __float_as_uint(x);
  unsigned int r = (u + 0x7FFFu + ((u >> 16) & 1u)) >> 16;
  return (unsigned short)r;
}
__device__ __forceinline__ float bf2f(unsigned short b) {
  return __uint_as_float(((unsigned int)b) << 16);
}

// ---------------------------------------------------------------------------
// CSR construction
// ---------------------------------------------------------------------------
__global__ void k_hist(const int* __restrict__ dst, int* __restrict__ deg, int E) {
  int e = blockIdx.x * blockDim.x + threadIdx.x;
  if (e < E) atomicAdd(&deg[dst[e]], 1);
}

__global__ __launch_bounds__(256) void k_csum(const int* __restrict__ deg,
                                              int* __restrict__ csum, int n) {
  __shared__ int ws[4];
  int t = threadIdx.x, lane = t & 63, w = t >> 6;
  int base = blockIdx.x * CH + t * 4;
  int s = 0;
  #pragma unroll
  for (int j = 0; j < 4; ++j) { int i = base + j; s += (i < n) ? deg[i] : 0; }
  #pragma unroll
  for (int off = 32; off > 0; off >>= 1) s += __shfl_down(s, off, 64);
  if (lane == 0) ws[w] = s;
  __syncthreads();
  if (t == 0) csum[blockIdx.x] = ws[0] + ws[1] + ws[2] + ws[3];
}

__global__ void k_coff(const int* __restrict__ csum, int* __restrict__ coff, int nb) {
  int lane = threadIdx.x & 63;
  int v = (lane < nb) ? csum[lane] : 0;
  int x = v;
  #pragma unroll
  for (int off = 1; off < 64; off <<= 1) {
    int u = __shfl_up(x, off, 64);
    if (lane >= off) x += u;
  }
  if (lane < nb) coff[lane] = x - v;
}

__global__ __launch_bounds__(256) void k_scanw(const int* __restrict__ deg,
                                               const int* __restrict__ coff,
                                               int* __restrict__ rs, int n) {
  __shared__ int ws[4];
  int t = threadIdx.x, lane = t & 63, w = t >> 6;
  int base = blockIdx.x * CH + t * 4;
  int d[4];
  #pragma unroll
  for (int j = 0; j < 4; ++j) { int i = base + j; d[j] = (i < n) ? deg[i] : 0; }
  int tt = d[0] + d[1] + d[2] + d[3];
  int x = tt;
  #pragma unroll
  for (int off = 1; off < 64; off <<= 1) {
    int u = __shfl_up(x, off, 64);
    if (lane >= off) x += u;
  }
  if (lane == 63) ws[w] = x;
  __syncthreads();
  if (t == 0) { int s = 0;
    #pragma unroll
    for (int j = 0; j < 4; ++j) { int tmp = ws[j]; ws[j] = s; s += tmp; } }
  __syncthreads();
  int excl = ws[w] + (x - tt) + coff[blockIdx.x];
  #pragma unroll
  for (int j = 0; j < 4; ++j) {
    int i = base + j;
    excl += d[j];
    if (i < n) rs[i + 1] = excl;
  }
  if (blockIdx.x == 0 && t == 0) rs[0] = 0;
}

__global__ void k_scatter(const int* __restrict__ src, const int* __restrict__ dst,
                          const int* __restrict__ rs, int* __restrict__ cursor,
                          int* __restrict__ esrc, int E) {
  int e = blockIdx.x * blockDim.x + threadIdx.x;
  if (e < E) {
    int d = dst[e];
    int pos = rs[d] + atomicAdd(&cursor[d], 1);
    esrc[pos] = src[e];
  }
}

// ---------------------------------------------------------------------------
// Weight conversion: Bt_hi/Bt_lo[col][k] bf16 (transposed, split) from
// [W1s(128); W1n(128)] stacked along k.
// ---------------------------------------------------------------------------
__global__ __launch_bounds__(256) void k_convW(const float* __restrict__ W1s,
                                               const float* __restrict__ W1n,
                                               unsigned short* __restrict__ Bth,
                                               unsigned short* __restrict__ Btl) {
  int k = blockIdx.x;          // 0..255
  int col = threadIdx.x;       // 0..255
  float w = (k < 128) ? W1s[(size_t)k * D_HID + col]
                      : W1n[(size_t)(k - 128) * D_HID + col];
  unsigned short hi = f2bf_rne(w);
  unsigned short lo = f2bf_rne(w - bf2f(hi));
  Bth[(size_t)col * 256 + k] = hi;
  Btl[(size_t)col * 256 + k] = lo;
}

// ---------------------------------------------------------------------------
// Layer-1 aggregation: mean of X over in-edges -> split-bf16 Mh/Ml[MPAD][128].
// One wave per node, lane owns 2 features, unrolled x4 for latency hiding.
// ---------------------------------------------------------------------------
__global__ void k_agg1(const float* __restrict__ X, const int* __restrict__ rs,
                       const int* __restrict__ esrc,
                       unsigned short* __restrict__ Mh,
                       unsigned short* __restrict__ Ml, int n) {
  int wid = (blockIdx.x * blockDim.x + threadIdx.x) >> 6;
  int lane = threadIdx.x & 63;
  if (wid >= n) return;
  int s0 = rs[wid], s1 = rs[wid + 1];
  float ax0 = 0.f, ay0 = 0.f, ax1 = 0.f, ay1 = 0.f;
  int e = s0;
  for (; e + 3 < s1; e += 4) {
    int i0 = esrc[e + 0], i1 = esrc[e + 1], i2 = esrc[e + 2], i3 = esrc[e + 3];
    float2 v0 = *(const float2*)(X + (size_t)i0 * D_IN + lane * 2);
    float2 v1 = *(const float2*)(X + (size_t)i1 * D_IN + lane * 2);
    float2 v2 = *(const float2*)(X + (size_t)i2 * D_IN + lane * 2);
    float2 v3 = *(const float2*)(X + (size_t)i3 * D_IN + lane * 2);
    ax0 += v0.x; ay0 += v0.y;
    ax1 += v1.x; ay1 += v1.y;
    ax0 += v2.x; ay0 += v2.y;
    ax1 += v3.x; ay1 += v3.y;
  }
  for (; e < s1; ++e) {
    int s = esrc[e];
    float2 v = *(const float2*)(X + (size_t)s * D_IN + lane * 2);
    ax0 += v.x; ay0 += v.y;
  }
  int d = s1 - s0;
  float inv = 1.0f / (float)(d > 1 ? d : 1);
  float mx = (ax0 + ax1) * inv, my = (ay0 + ay1) * inv;
  unsigned short hx = f2bf_rne(mx), hy = f2bf_rne(my);
  unsigned short lx = f2bf_rne(mx - bf2f(hx)), ly = f2bf_rne(my - bf2f(hy));
  *(ushort2*)(Mh + (size_t)wid * 128 + lane * 2) = make_ushort2(hx, hy);
  *(ushort2*)(Ml + (size_t)wid * 128 + lane * 2) = make_ushort2(lx, ly);
}

// ---------------------------------------------------------------------------
// MFMA GEMM (split-bf16, 3 terms) with mfma_f32_32x32x16_bf16.
// BM=64 x BN=256, K=256, kt-chunks of 32. 4 waves as 2M x 2N: each wave
// computes 32 rows x 128 cols (4 col-tiles of 32), doubling FLOP per LDS
// byte vs 16x16 (20 ds_read_b128 per chunk vs 34).
// Fragment layout (lane l): elem (l&31, (l>>5)*8 + i) — staged lane-linear so
// every frag read is a linear 16B/lane ds_read_b128 (conflict-free).
// k<128: A from fp32 X, converted in-kernel; k>=128: A from Mh/Ml via
// global_load_lds with pre-permuted per-lane global source.
// Fused epilogue: h=relu(acc+b1); SP[row]={h.W2s,h.W2n} (atomic-free).
// ---------------------------------------------------------------------------
__global__ __launch_bounds__(256, 3) void k_gemm1(
    const float* __restrict__ X,
    const unsigned short* __restrict__ Mh, const unsigned short* __restrict__ Ml,
    const unsigned short* __restrict__ Bth, const unsigned short* __restrict__ Btl,
    const float* __restrict__ b1, const float* __restrict__ W2s,
    const float* __restrict__ W2n, float* __restrict__ SP, int n) {
  // sA[m-half][kstep][hi/lo]: 32 rows x 16 k, lane-linear (lane l at short l*8)
  __shared__ __align__(16) unsigned short sA[2][2][2][512];   //  8 KB
  __shared__ __align__(16) unsigned short sB[8][2][2][512];   // 32 KB

  const int tid = threadIdx.x;
  const int w = tid >> 6;        // wave 0..3
  const int l = tid & 63;
  const int wm = w & 1, wn = w >> 1;   // compute: rows wm*32+, cols wn*128+
  const int r32 = l & 31;              // row/col within 32
  const int kh = l >> 5;               // k-half -> 8-elem offset
  const int m0 = blockIdx.x * 64;

  f32x16 acc[4];
  #pragma unroll
  for (int q = 0; q < 4; ++q) acc[q] = (f32x16)0.f;

  // staging assignment: wave w stages A chunk (m=w&1, kstep=w>>1)
  const int sm = w & 1, sk = w >> 1;
  const int arow = m0 + sm * 32 + r32;
  const int xrow = (arow < n) ? arow : (n - 1);

  for (int ks = 0; ks < 8; ++ks) {
    const int kt = ks * 32;
    // ---- stage A (this wave's chunk) ----
    if (kt < 128) {
      const float* src = X + (size_t)xrow * D_IN + kt + sk * 16 + kh * 8;
      float4 u0 = *(const float4*)(src);
      float4 u1 = *(const float4*)(src + 4);
      float v[8] = {u0.x, u0.y, u0.z, u0.w, u1.x, u1.y, u1.z, u1.w};
      ushort8 hh, ll;
      #pragma unroll
      for (int i = 0; i < 8; ++i) {
        unsigned short h = f2bf_rne(v[i]);
        hh[i] = h;
        ll[i] = f2bf_rne(v[i] - bf2f(h));
      }
      *(ushort8*)(&sA[sm][sk][0][l * 8]) = hh;
      *(ushort8*)(&sA[sm][sk][1][l * 8]) = ll;
    } else {
      const unsigned short* mh = Mh + (size_t)arow * 128 + (kt - 128) + sk * 16 + kh * 8;
      const unsigned short* ml = Ml + (size_t)arow * 128 + (kt - 128) + sk * 16 + kh * 8;
      __builtin_amdgcn_global_load_lds((AS1 const void*)mh, (AS3 void*)&sA[sm][sk][0][0], 16, 0, 0);
      __builtin_amdgcn_global_load_lds((AS1 const void*)ml, (AS3 void*)&sA[sm][sk][1][0], 16, 0, 0);
    }
    // ---- stage B: wave w stages col-tiles 2w, 2w+1 (both ksteps, hi+lo) ----
    #pragma unroll
    for (int q = 0; q < 2; ++q) {
      int ct = w * 2 + q;
      #pragma unroll
      for (int kstep = 0; kstep < 2; ++kstep) {
        const unsigned short* bh = Bth + (size_t)(ct * 32 + r32) * 256 + kt + kstep * 16 + kh * 8;
        const unsigned short* bl = Btl + (size_t)(ct * 32 + r32) * 256 + kt + kstep * 16 + kh * 8;
        __builtin_amdgcn_global_load_lds((AS1 const void*)bh, (AS3 void*)&sB[ct][kstep][0][0], 16, 0, 0);
        __builtin_amdgcn_global_load_lds((AS1 const void*)bl, (AS3 void*)&sB[ct][kstep][1][0], 16, 0, 0);
      }
    }
    __syncthreads();

    // ---- compute: 2 ksteps x 4 col-tiles x 3 split terms ----
    #pragma unroll
    for (int kstep = 0; kstep < 2; ++kstep) {
      bf16x8 ah = *(const bf16x8*)(&sA[wm][kstep][0][l * 8]);
      bf16x8 al = *(const bf16x8*)(&sA[wm][kstep][1][l * 8]);
      #pragma unroll
      for (int q = 0; q < 4; ++q) {
        int ct = wn * 4 + q;
        bf16x8 bh = *(const bf16x8*)(&sB[ct][kstep][0][l * 8]);
        bf16x8 bl = *(const bf16x8*)(&sB[ct][kstep][1][l * 8]);
        acc[q] = __builtin_amdgcn_mfma_f32_32x32x16_bf16(ah, bh, acc[q], 0, 0, 0);
        acc[q] = __builtin_amdgcn_mfma_f32_32x32x16_bf16(ah, bl, acc[q], 0, 0, 0);
        acc[q] = __builtin_amdgcn_mfma_f32_32x32x16_bf16(al, bh, acc[q], 0, 0, 0);
      }
    }
    __syncthreads();
  }

  // ---- fused epilogue ----
  // lane's 4 cols: wn*128 + q*32 + r32
  float b1v[4]; float2 w2sv[4], w2nv[4];
  #pragma unroll
  for (int q = 0; q < 4; ++q) {
    int col = wn * 128 + q * 32 + r32;
    b1v[q] = b1[col];
    w2sv[q] = *(const float2*)(W2s + (size_t)col * 2);
    w2nv[q] = *(const float2*)(W2n + (size_t)col * 2);
  }
  float4* fpart = (float4*)&sB[0][0][0][0];   // [2 wn][64 rows] partials
  #pragma unroll
  for (int j = 0; j < 16; ++j) {
    float s0 = 0.f, s1 = 0.f, p0 = 0.f, p1 = 0.f;
    #pragma unroll
    for (int q = 0; q < 4; ++q) {
      float h = fmaxf(acc[q][j] + b1v[q], 0.f);
      s0 += h * w2sv[q].x; s1 += h * w2sv[q].y;
      p0 += h * w2nv[q].x; p1 += h * w2nv[q].y;
    }
    #pragma unroll
    for (int off = 1; off < 32; off <<= 1) {
      s0 += __shfl_xor(s0, off, 64);
      s1 += __shfl_xor(s1, off, 64);
      p0 += __shfl_xor(p0, off, 64);
      p1 += __shfl_xor(p1, off, 64);
    }
    if (r32 == 0) {
      int row = wm * 32 + (j & 3) + 8 * (j >> 2) + 4 * kh;  // C/D 32x32 layout
      float4 o; o.x = s0; o.y = s1; o.z = p0; o.w = p1;
      fpart[wn * 64 + row] = o;
    }
  }
  __syncthreads();
  if (w == 0) {   // combine the two wn halves, store SP
    float4 a = fpart[l], b = fpart[64 + l];
    float4 o; o.x = a.x + b.x; o.y = a.y + b.y; o.z = a.z + b.z; o.w = a.w + b.w;
    *(float4*)(SP + (size_t)(m0 + l) * 4) = o;
  }
}

// ---------------------------------------------------------------------------
// Layer-2 aggregation over projected P (= SP[:,2:4], 8B/edge) + final add.
// ---------------------------------------------------------------------------
__global__ void k_agg2(const float* __restrict__ SP,
                       const int* __restrict__ rs, const int* __restrict__ esrc,
                       const float* __restrict__ b2,
                       float* __restrict__ out, int n) {
  int nid = blockIdx.x * blockDim.x + threadIdx.x;
  if (nid >= n) return;
  int s0 = rs[nid], s1 = rs[nid + 1];
  float a00 = 0.f, a01 = 0.f, a10 = 0.f, a11 = 0.f;
  int e = s0;
  for (; e + 3 < s1; e += 4) {
    int i0 = esrc[e + 0], i1 = esrc[e + 1], i2 = esrc[e + 2], i3 = esrc[e + 3];
    float2 p0 = *(const float2*)(SP + (size_t)i0 * 4 + 2);
    float2 p1 = *(const float2*)(SP + (size_t)i1 * 4 + 2);
    float2 p2 = *(const float2*)(SP + (size_t)i2 * 4 + 2);
    float2 p3 = *(const float2*)(SP + (size_t)i3 * 4 + 2);
    a00 += p0.x; a01 += p0.y;
    a10 += p1.x; a11 += p1.y;
    a00 += p2.x; a01 += p2.y;
    a10 += p3.x; a11 += p3.y;
  }
  for (; e < s1; ++e) {
    int s = esrc[e];
    float2 p = *(const float2*)(SP + (size_t)s * 4 + 2);
    a00 += p.x; a01 += p.y;
  }
  int d = s1 - s0;
  float inv = 1.0f / (float)(d > 1 ? d : 1);
  float2 sv = *(const float2*)(SP + (size_t)nid * 4);
  float2 o;
  o.x = sv.x + b2[0] + (a00 + a10) * inv;
  o.y = sv.y + b2[1] + (a01 + a11) * inv;
  *(float2*)(out + (size_t)nid * 2) = o;
}

// ---------------------------------------------------------------------------
extern "C" void kernel_launch(void* const* d_in, const int* in_sizes, int n_in,
                              void* d_out, int out_size, void* d_ws, size_t ws_size,
                              hipStream_t stream) {
  const float* X   = (const float*)d_in[0];
  const int*   src = (const int*)d_in[1];
  const int*   dst = (const int*)d_in[2];
  const float* W1s = (const float*)d_in[3];
  const float* W1n = (const float*)d_in[4];
  const float* b1  = (const float*)d_in[5];
  const float* W2s = (const float*)d_in[6];
  const float* W2n = (const float*)d_in[7];
  const float* b2  = (const float*)d_in[8];
  float* out = (float*)d_out;

  const int N = in_sizes[0] / D_IN;   // 50000
  const int E = in_sizes[1];          // 640000
  const int NB = (N + CH - 1) / CH;   // 49 scan chunks (<= 64)

  // workspace layout (16B-aligned sections), ~32 MB total
  int* deg    = (int*)d_ws;                         // [N]
  int* cursor = deg + N;                            // [N]
  int* rs     = cursor + N;                         // [N+8]
  int* csum   = rs + (N + 8);                       // [64]
  int* coff   = csum + 64;                          // [64]
  int* esrc   = coff + 64;                          // [E]
  float* SP   = (float*)(esrc + E);                 // [MPAD][4] {S0,S1,P0,P1}
  unsigned short* Mh  = (unsigned short*)(SP + (size_t)MPAD * 4);  // [MPAD][128]
  unsigned short* Ml  = Mh + (size_t)MPAD * 128;                   // [MPAD][128]
  unsigned short* Bth = Ml + (size_t)MPAD * 128;                   // [256][256]
  unsigned short* Btl = Bth + 256 * 256;                           // [256][256]

  hipMemsetAsync(deg, 0, sizeof(int) * (size_t)2 * N, stream);     // deg+cursor

  int eb = (E + 255) / 256;
  k_convW  <<<256, 256, 0, stream>>>(W1s, W1n, Bth, Btl);
  k_hist   <<<eb, 256, 0, stream>>>(dst, deg, E);
  k_csum   <<<NB, 256, 0, stream>>>(deg, csum, N);
  k_coff   <<<1, 64, 0, stream>>>(csum, coff, NB);
  k_scanw  <<<NB, 256, 0, stream>>>(deg, coff, rs, N);
  k_scatter<<<eb, 256, 0, stream>>>(src, dst, rs, cursor, esrc, E);
  k_agg1   <<<(N + 3) / 4, 256, 0, stream>>>(X, rs, esrc, Mh, Ml, N);
  k_gemm1  <<<MPAD / 64, 256, 0, stream>>>(X, Mh, Ml, Bth, Btl,
                                           b1, W2s, W2n, SP, N);
  k_agg2   <<<(N + 255) / 256, 256, 0, stream>>>(SP, rs, esrc, b2, out, N);
}